// Round 4
// baseline (395.202 us; speedup 1.0000x reference)
//
#include <hip/hip_runtime.h>
#include <cstdint>
#include <cstddef>

// Problem constants (B=8, S=2048, D=1024)
#define BATCH 8
#define SEQ   2048
#define DM    1024

typedef _Float16 half8 __attribute__((ext_vector_type(8)));
typedef _Float16 half4v __attribute__((ext_vector_type(4)));
typedef float floatx16 __attribute__((ext_vector_type(16)));
typedef float float4v __attribute__((ext_vector_type(4)));

#define GLOBAL_AS __attribute__((address_space(1)))
#define LDS_AS    __attribute__((address_space(3)))

// Async global->LDS, 16B per lane. LDS dest = wave-uniform base + lane*16.
__device__ __forceinline__ void gl_lds16(const _Float16* g, _Float16* l) {
    __builtin_amdgcn_global_load_lds((const GLOBAL_AS void*)g, (LDS_AS void*)l, 16, 0, 0);
}

// ---------------------------------------------------------------------------
// Stage one half-tile: 128 rows x 64 cols (f16), chunk-XOR swizzled
// (slot s of row r holds global chunk s ^ (r&7)). 512 thr, 2 loads each.
// ---------------------------------------------------------------------------
__device__ __forceinline__ void stage128(const _Float16* __restrict__ g, int ld, int k0,
                                         _Float16* l, int wave, int lane) {
    const int rw = wave * 8 + (lane >> 3);
    const int sl = lane & 7;
    #pragma unroll
    for (int i = 0; i < 2; i++) {
        const int r = i * 64 + rw;
        gl_lds16(g + (size_t)r * ld + k0 + ((sl ^ (r & 7)) << 3),
                 l + ((i * 64 + wave * 8) << 6));
    }
}

#define SCHED __builtin_amdgcn_sched_barrier(0)
#define BAR   __builtin_amdgcn_s_barrier()
#define WAIT_VM0   asm volatile("s_waitcnt vmcnt(0)" ::: "memory")
#define WAIT_LGKM6 asm volatile("s_waitcnt lgkmcnt(6)" ::: "memory")
#define WAIT_LGKM0 asm volatile("s_waitcnt lgkmcnt(0)" ::: "memory")

// Read one k-step's fragment set (4 A + 2 B = 6 x ds_read_b128).
// 32x32x16 operand layout: row = lane&31, k-octet = lane>>5 (K=16 = 2 octets).
// Frag rows span 32 rows -> 8 swizzle slots = 4-way bank alias (accepted;
// hidden under the MFMA burst).
#define RD(AV, BV, BUF, KS)                                                   \
    _Pragma("unroll")                                                         \
    for (int f_ = 0; f_ < 4; f_++) {                                          \
        const int r_ = f_ * 32 + l31;                                         \
        AV[f_] = *(const half8*)&SA[BUF][hA + r_ * 64 + ((((KS)*2 + o0) ^ (r_ & 7)) << 3)]; \
    }                                                                         \
    _Pragma("unroll")                                                         \
    for (int g_ = 0; g_ < 2; g_++) {                                          \
        const int r_ = rb + g_ * 32;                                          \
        BV[g_] = *(const half8*)&SB[BUF][hB + r_ * 64 + ((((KS)*2 + o0) ^ (r_ & 7)) << 3)]; \
    }

// One k-step's 8-MFMA burst (32x32x16), all acc tiles independent.
#define MM(AV, BV)                                                            \
    __builtin_amdgcn_s_setprio(1);                                            \
    _Pragma("unroll")                                                         \
    for (int f_ = 0; f_ < 4; f_++)                                            \
        _Pragma("unroll")                                                     \
        for (int g_ = 0; g_ < 2; g_++)                                        \
            acc[f_][g_] = __builtin_amdgcn_mfma_f32_32x32x16_f16(             \
                AV[f_], BV[g_], acc[f_][g_], 0, 0, 0);                        \
    __builtin_amdgcn_s_setprio(0);

// ---------------------------------------------------------------------------
// 256x256 C = A.B^T, register-rotated engine, BK=64, 512 thr, 8 waves.
// R4: 32x32x16 MFMA + k-step register double-buffer + ONE barrier per K-tile.
//   - reads for k-step i+1 issue BEFORE the MFMA burst of k-step i -> LDS
//     pipe runs concurrently with MFMA pipe (intra-wave overlap, no lockstep)
//   - counted lgkmcnt(6): 12 outstanding ds_reads -> drain the old set only
//   - stage kt+1 -> buf^1 at iter head (safe: all reads of buf^1 drained
//     before previous iter's barrier); vmcnt(0) gate at tail = full K-tile
//     (~2000 cyc) of prefetch lead >> HBM latency
//   - WAR on alternating frag sets pins MFMA/read order; SCHED after each
//     wait stops MFMA hoisting past inline-asm waits (rule #18)
// Ledger (per wave): lgkm 6->12->drain6 x3 ->0; vm 8 per K-tile ->0 at gate.
// ---------------------------------------------------------------------------
__device__ __forceinline__ void gemm256_rr(
    const _Float16* __restrict__ A, const _Float16* __restrict__ B,
    int lda, int ldb, int nkt,
    _Float16 (&SA)[2][16384], _Float16 (&SB)[2][16384],
    floatx16 (&acc)[4][2])
{
    const int t = threadIdx.x;
    const int wave = t >> 6, lane = t & 63;
    const int l31 = lane & 31, o0 = lane >> 5;
    const int wm = wave >> 2, wn = wave & 3;

    const int hA = wm * 8192;          // A rows wm*128..+127 -> half wm
    const int hB = (wn >> 1) * 8192;   // B rows (cols of C) half = wn>>1
    const int rb = (wn & 1) * 64 + l31;

    const _Float16* A128 = A + (size_t)128 * lda;
    const _Float16* B128 = B + (size_t)128 * ldb;

    half8 a0[4], b0[2], a1[4], b1[2];

    // Prologue: stage K-tile 0 into buf0, preload ks0 -> set0.
    stage128(A,    lda, 0, &SA[0][0],    wave, lane);
    stage128(A128, lda, 0, &SA[0][8192], wave, lane);
    stage128(B,    ldb, 0, &SB[0][0],    wave, lane);
    stage128(B128, ldb, 0, &SB[0][8192], wave, lane);
    WAIT_VM0;
    BAR; SCHED;
    RD(a0, b0, 0, 0);

    for (int kt = 0; kt < nkt; ++kt) {
        const int bs = kt & 1;
        const bool more = (kt + 1) < nkt;
        if (more) {
            const int k1 = (kt + 1) * 64;
            stage128(A,    lda, k1, &SA[bs ^ 1][0],    wave, lane);
            stage128(A128, lda, k1, &SA[bs ^ 1][8192], wave, lane);
            stage128(B,    ldb, k1, &SB[bs ^ 1][0],    wave, lane);
            stage128(B128, ldb, k1, &SB[bs ^ 1][8192], wave, lane);
        }
        SCHED;
        RD(a1, b1, bs, 1);
        WAIT_LGKM6; SCHED;
        MM(a0, b0);                 // ks0
        RD(a0, b0, bs, 2);
        WAIT_LGKM6; SCHED;
        MM(a1, b1);                 // ks1
        RD(a1, b1, bs, 3);
        WAIT_LGKM6; SCHED;
        MM(a0, b0);                 // ks2
        WAIT_LGKM0;                 // drain ks3 reads before barrier
        if (more) {
            WAIT_VM0;               // next K-tile landed (issued ~1 K-tile ago)
            BAR; SCHED;
            RD(a0, b0, bs ^ 1, 0);  // preload next tile's ks0
        }
        MM(a1, b1);                 // ks3 (data drained pre-barrier)
    }
}

// ---------------------------------------------------------------------------
// Kernel 1: fp32 -> fp16, vectorized float4 -> half4.  (unchanged)
// ---------------------------------------------------------------------------
__global__ __launch_bounds__(256) void convert_inputs(
    const float* __restrict__ src,
    const float* __restrict__ Wk, const float* __restrict__ Wv, const float* __restrict__ Wq,
    _Float16* __restrict__ Xh, _Float16* __restrict__ Wh)
{
    const int gid = blockIdx.x * 256 + threadIdx.x;
    const int gs  = gridDim.x * 256;
    const int nX4 = BATCH * SEQ * DM / 4;
    const int nW4 = DM * DM / 4;
    const float4v* s4  = (const float4v*)src;
    const float4v* wk4 = (const float4v*)Wk;
    const float4v* wv4 = (const float4v*)Wv;
    const float4v* wq4 = (const float4v*)Wq;
    half4v* x4 = (half4v*)Xh;
    half4v* w4 = (half4v*)Wh;
    for (int i = gid; i < nX4; i += gs) {
        float4v v = s4[i];
        half4v h;
        #pragma unroll
        for (int e = 0; e < 4; e++) h[e] = (_Float16)v[e];
        x4[i] = h;
    }
    for (int i = gid; i < nW4; i += gs) {
        float4v a = wk4[i], b = wv4[i], c = wq4[i];
        half4v ha, hb, hc;
        #pragma unroll
        for (int e = 0; e < 4; e++) { ha[e] = (_Float16)a[e]; hb[e] = (_Float16)b[e]; hc[e] = (_Float16)c[e]; }
        w4[i]           = ha;
        w4[nW4 + i]     = hb;
        w4[2 * nW4 + i] = hc;
    }
}

// ---------------------------------------------------------------------------
// Kernel 2: QKV projection, 768 blocks x 512 thr, 256^2 tiles, XCD-bijective.
//   z=0: K[s][d]  = X.Wk^T + bk
//   z=1: Vt[d][s] = Wv.X^T + bv[d]
//   z=2: Q[s][d]  = X.Wq^T + bq
// C/D map (32x32x16): col = lane&31, row = (reg&3)+8*(reg>>2)+4*(lane>>5).
// ---------------------------------------------------------------------------
__global__ __launch_bounds__(512, 2) void qkv_gemm(
    const _Float16* __restrict__ Xh, const _Float16* __restrict__ Wh,
    const float* __restrict__ bk, const float* __restrict__ bv, const float* __restrict__ bq,
    _Float16* __restrict__ Kh, _Float16* __restrict__ Vt, _Float16* __restrict__ Qh)
{
    __shared__ __align__(16) _Float16 SA[2][16384];
    __shared__ __align__(16) _Float16 SB[2][16384];
    const int L = blockIdx.x;                 // 768 = 8 XCD x 96
    const int lid = (L & 7) * 96 + (L >> 3);
    const int z = lid >> 8;
    const int r = lid & 255;
    int by, bx;
    const _Float16 *A, *B;
    if (z == 1) {
        by = r & 3; bx = r >> 2;              // consecutive lids share X panel
        A = Wh + (size_t)DM * DM + (size_t)by * 256 * DM;
        B = Xh + (size_t)bx * 256 * DM;
    } else {
        by = r >> 2; bx = r & 3;              // consecutive lids share X panel
        A = Xh + (size_t)by * 256 * DM;
        B = Wh + (z ? (size_t)2 * DM * DM : (size_t)0) + (size_t)bx * 256 * DM;
    }
    floatx16 acc[4][2] = {};
    gemm256_rr(A, B, DM, DM, 16, SA, SB, acc);

    const int t = threadIdx.x, wave = t >> 6, lane = t & 63;
    const int l31 = lane & 31, o0 = lane >> 5;
    const int wm = wave >> 2, wn = wave & 3;
    if (z == 1) {
        #pragma unroll
        for (int f = 0; f < 4; f++)
            #pragma unroll
            for (int g = 0; g < 2; g++)
                #pragma unroll
                for (int rg = 0; rg < 16; rg++) {
                    const int d  = by * 256 + wm * 128 + f * 32 + 4 * o0 + (rg & 3) + 8 * (rg >> 2);
                    const int sg = bx * 256 + wn * 64 + g * 32 + l31;
                    const int b = sg >> 11, s = sg & (SEQ - 1);
                    Vt[((size_t)b * DM + d) * SEQ + s] = (_Float16)(acc[f][g][rg] + bv[d]);
                }
    } else {
        const float* bias = z ? bq : bk;
        _Float16* outp    = z ? Qh : Kh;
        #pragma unroll
        for (int f = 0; f < 4; f++)
            #pragma unroll
            for (int g = 0; g < 2; g++)
                #pragma unroll
                for (int rg = 0; rg < 16; rg++) {
                    const int row = by * 256 + wm * 128 + f * 32 + 4 * o0 + (rg & 3) + 8 * (rg >> 2);
                    const int col = bx * 256 + wn * 64 + g * 32 + l31;
                    outp[(size_t)row * DM + col] = (_Float16)(acc[f][g][rg] + bias[col]);
                }
    }
}

// ---------------------------------------------------------------------------
// Kernel 3: scores (fp16) = Q.K^T * (1/32) + pad[b][k]; lower-tri 256-tiles.
// 288 blocks = 8 batches x 36 tri-tiles; XCD x owns batch x.
// ---------------------------------------------------------------------------
__global__ __launch_bounds__(512, 2) void scores_gemm(
    const _Float16* __restrict__ Qh, const _Float16* __restrict__ Kh,
    const float* __restrict__ pad, _Float16* __restrict__ Sc)
{
    __shared__ __align__(16) _Float16 SA[2][16384];
    __shared__ __align__(16) _Float16 SB[2][16384];
    const int L = blockIdx.x;                 // 288 = 8 XCD x 36
    const int lid = (L & 7) * 36 + (L >> 3);
    const int b = lid / 36, tri = lid - b * 36;
    int by = 0;
    #pragma unroll
    for (int u = 1; u <= 7; u++) if (tri >= (u * (u + 1)) / 2) by = u;
    const int bx = tri - (by * (by + 1)) / 2;

    const _Float16* A = Qh + ((size_t)b * SEQ + by * 256) * DM;
    const _Float16* B = Kh + ((size_t)b * SEQ + bx * 256) * DM;
    floatx16 acc[4][2] = {};
    gemm256_rr(A, B, DM, DM, 16, SA, SB, acc);

    const int t = threadIdx.x, wave = t >> 6, lane = t & 63;
    const int l31 = lane & 31, o0 = lane >> 5;
    const int wm = wave >> 2, wn = wave & 3;
    #pragma unroll
    for (int f = 0; f < 4; f++)
        #pragma unroll
        for (int g = 0; g < 2; g++)
            #pragma unroll
            for (int rg = 0; rg < 16; rg++) {
                const int row = by * 256 + wm * 128 + f * 32 + 4 * o0 + (rg & 3) + 8 * (rg >> 2);
                const int col = bx * 256 + wn * 64 + g * 32 + l31;
                Sc[((size_t)b * SEQ + row) * SEQ + col] =
                    (_Float16)(acc[f][g][rg] * 0.03125f + pad[b * SEQ + col]);
            }
}

// ---------------------------------------------------------------------------
// Kernel 4: in-place row softmax over k in [0,q]; zeros for k in (q, kmaxr).
// kmaxr 256-granular (pv reads 256-wide tiles).
// ---------------------------------------------------------------------------
__global__ __launch_bounds__(256) void softmax_rows(_Float16* __restrict__ Sc)
{
    const int bid = blockIdx.x;
    const int b = bid >> 11, q = bid & (SEQ - 1);
    _Float16* row = Sc + ((size_t)b * SEQ + q) * SEQ;
    const int n = q + 1;
    const int kmaxr = ((q >> 8) + 1) << 8;
    const int t = threadIdx.x;
    const int c0 = t * 8;
    const bool active = (c0 < kmaxr);
    __shared__ float red[4];

    half8 v = {};
    if (active) v = *(const half8*)(row + c0);
    float f[8];
    float m = -3.0e38f;
    #pragma unroll
    for (int e = 0; e < 8; e++) {
        f[e] = (active && (c0 + e < n)) ? (float)v[e] : -3.0e38f;
        m = fmaxf(m, f[e]);
    }
    #pragma unroll
    for (int o = 32; o > 0; o >>= 1) m = fmaxf(m, __shfl_down(m, o));
    if ((t & 63) == 0) red[t >> 6] = m;
    __syncthreads();
    m = fmaxf(fmaxf(red[0], red[1]), fmaxf(red[2], red[3]));

    float ex[8], s = 0.f;
    #pragma unroll
    for (int e = 0; e < 8; e++) {
        ex[e] = (f[e] > -1.0e38f) ? __expf(f[e] - m) : 0.f;
        s += ex[e];
    }
    #pragma unroll
    for (int o = 32; o > 0; o >>= 1) s += __shfl_down(s, o);
    __syncthreads();
    if ((t & 63) == 0) red[t >> 6] = s;
    __syncthreads();
    s = red[0] + red[1] + red[2] + red[3];

    if (active) {
        const float inv = 1.0f / s;
        half8 o8;
        #pragma unroll
        for (int e = 0; e < 8; e++) o8[e] = (_Float16)(ex[e] * inv);
        *(half8*)(row + c0) = o8;
    }
}

// ---------------------------------------------------------------------------
// Kernel 5: O[q][d] = sum_k P[q][k] * Vt[d][k]; K-loop stops after q-tile.
// 256 blocks, 1/CU; XCD x owns batch x; longest tiles (by=7) first.
// ---------------------------------------------------------------------------
__global__ __launch_bounds__(512, 2) void pv_gemm(
    const _Float16* __restrict__ P, const _Float16* __restrict__ Vt,
    float* __restrict__ out)
{
    __shared__ __align__(16) _Float16 SA[2][16384];
    __shared__ __align__(16) _Float16 SB[2][16384];
    const int L = blockIdx.x;                 // 256 = 8 XCD x 32
    const int lid = (L & 7) * 32 + (L >> 3);
    const int b = lid >> 5, r = lid & 31;
    const int by = 7 - (r >> 2);              // long tiles first
    const int bx = r & 3;

    const _Float16* A = P  + ((size_t)b * SEQ + by * 256) * SEQ;
    const _Float16* B = Vt + ((size_t)b * DM  + bx * 256) * SEQ;
    const int nkt = (by + 1) * 4;             // K = (by+1)*256, P zero beyond
    floatx16 acc[4][2] = {};
    gemm256_rr(A, B, SEQ, SEQ, nkt, SA, SB, acc);

    const int t = threadIdx.x, wave = t >> 6, lane = t & 63;
    const int l31 = lane & 31, o0 = lane >> 5;
    const int wm = wave >> 2, wn = wave & 3;
    #pragma unroll
    for (int f = 0; f < 4; f++)
        #pragma unroll
        for (int g = 0; g < 2; g++)
            #pragma unroll
            for (int rg = 0; rg < 16; rg++) {
                const int row = by * 256 + wm * 128 + f * 32 + 4 * o0 + (rg & 3) + 8 * (rg >> 2);
                const int col = bx * 256 + wn * 64 + g * 32 + l31;
                out[((size_t)b * SEQ + row) * DM + col] = acc[f][g][rg];
            }
}

// ---------------------------------------------------------------------------
// Workspace layout (bytes) — total 174,063,616:
//   Wh @ 0         :  6,291,456  (3x1024x1024 fp16)
//   Qh @ 6291456   : 33,554,432
//   Kh @ 39845888  : 33,554,432
//   Vt @ 73400320  : 33,554,432  ([B][D][S] fp16, written directly by qkv z=1)
//   Sc @ 106954752 : 67,108,864  (8x2048x2048 fp16; softmax in-place -> P)
// Xh (fp16 src, 33.5 MB) lives in d_out; dead before pv_gemm writes out.
// ---------------------------------------------------------------------------
extern "C" void kernel_launch(void* const* d_in, const int* in_sizes, int n_in,
                              void* d_out, int out_size, void* d_ws, size_t ws_size,
                              hipStream_t stream) {
    const float* src = (const float*)d_in[0];
    const float* pad = (const float*)d_in[1];
    // d_in[2] = causal mask, handled analytically
    const float* Wk = (const float*)d_in[3];
    const float* bk = (const float*)d_in[4];
    const float* Wv = (const float*)d_in[5];
    const float* bv = (const float*)d_in[6];
    const float* Wq = (const float*)d_in[7];
    const float* bq = (const float*)d_in[8];
    float* out = (float*)d_out;

    char* ws = (char*)d_ws;
    _Float16* Wh = (_Float16*)(ws);
    _Float16* Qh = (_Float16*)(ws + 6291456);
    _Float16* Kh = (_Float16*)(ws + 39845888);
    _Float16* Vt = (_Float16*)(ws + 73400320);
    _Float16* Sc = (_Float16*)(ws + 106954752);
    _Float16* Xh = (_Float16*)d_out;  // scratch inside out buffer

    convert_inputs<<<2048, 256, 0, stream>>>(src, Wk, Wv, Wq, Xh, Wh);
    qkv_gemm<<<768, 512, 0, stream>>>(Xh, Wh, bk, bv, bq, Kh, Vt, Qh);
    scores_gemm<<<288, 512, 0, stream>>>(Qh, Kh, pad, Sc);
    softmax_rows<<<BATCH * SEQ, 256, 0, stream>>>(Sc);
    pv_gemm<<<256, 512, 0, stream>>>(Sc, Vt, out);
}

// Round 5
// 382.938 us; speedup vs baseline: 1.0320x; 1.0320x over previous
//
#include <hip/hip_runtime.h>
#include <cstdint>
#include <cstddef>

// Problem constants (B=8, S=2048, D=1024)
#define BATCH 8
#define SEQ   2048
#define DM    1024

typedef _Float16 half8 __attribute__((ext_vector_type(8)));
typedef _Float16 half4v __attribute__((ext_vector_type(4)));
typedef float floatx4 __attribute__((ext_vector_type(4)));
typedef float float4v __attribute__((ext_vector_type(4)));

#define GLOBAL_AS __attribute__((address_space(1)))
#define LDS_AS    __attribute__((address_space(3)))

// Async global->LDS, 16B per lane. LDS dest = wave-uniform base + lane*16.
__device__ __forceinline__ void gl_lds16(const _Float16* g, _Float16* l) {
    __builtin_amdgcn_global_load_lds((const GLOBAL_AS void*)g, (LDS_AS void*)l, 16, 0, 0);
}

// ---------------------------------------------------------------------------
// Stage one half-tile: 128 rows x 64 cols (f16), chunk-XOR swizzled
// (slot s of row r holds global chunk s ^ (r&7)). 512 thr, 2 loads each.
// ---------------------------------------------------------------------------
__device__ __forceinline__ void stage128(const _Float16* __restrict__ g, int ld, int k0,
                                         _Float16* l, int wave, int lane) {
    const int rw = wave * 8 + (lane >> 3);
    const int sl = lane & 7;
    #pragma unroll
    for (int i = 0; i < 2; i++) {
        const int r = i * 64 + rw;
        gl_lds16(g + (size_t)r * ld + k0 + ((sl ^ (r & 7)) << 3),
                 l + ((i * 64 + wave * 8) << 6));
    }
}

#define SCHED __builtin_amdgcn_sched_barrier(0)
#define BAR   __builtin_amdgcn_s_barrier()
#define WAIT_VM0    asm volatile("s_waitcnt vmcnt(0)" ::: "memory")
#define WAIT_LGKM12 asm volatile("s_waitcnt lgkmcnt(12)" ::: "memory")
#define WAIT_LGKM0  asm volatile("s_waitcnt lgkmcnt(0)" ::: "memory")

// One k-half's full fragment set: 8 A + 4 B = 12 x ds_read_b128.
// 16x16x32 pattern (PROVEN conflict-free R2/R3: 16 rows x 8 slots = 2-way
// within each 16-lane phase, SQ_LDS_BANK_CONFLICT == 0 measured).
// AV[i]: i = h*4 + ii -> row (wm*64 + h*128 + ii*16 + l15); BV[j]: j = cols
// (wn*16 + (j&1)*64 + (j>>1)*128 + l15). SL selects the k-half's slots.
#define RD_SET(AV, BV, BUF, SL)                                               \
    _Pragma("unroll")                                                         \
    for (int i_ = 0; i_ < 4; i_++)                                            \
        AV[i_] = *(const half8*)&SA[BUF][aoff + i_ * 1024 + (SL)];            \
    _Pragma("unroll")                                                         \
    for (int i_ = 0; i_ < 4; i_++)                                            \
        AV[4 + i_] = *(const half8*)&SA[BUF][aoff + 8192 + i_ * 1024 + (SL)]; \
    _Pragma("unroll")                                                         \
    for (int j_ = 0; j_ < 2; j_++)                                            \
        BV[j_] = *(const half8*)&SB[BUF][boff + j_ * 4096 + (SL)];            \
    _Pragma("unroll")                                                         \
    for (int j_ = 0; j_ < 2; j_++)                                            \
        BV[2 + j_] = *(const half8*)&SB[BUF][boff + 8192 + j_ * 4096 + (SL)];

// One k-half's 32-MFMA burst over the full 8x4 acc tile, setprio-wrapped.
// Per-acc accumulation order across the kt = half0 then half1 (same as R2).
#define MM_SET(AV, BV)                                                        \
    __builtin_amdgcn_s_setprio(1);                                            \
    _Pragma("unroll")                                                         \
    for (int i_ = 0; i_ < 8; i_++)                                            \
        _Pragma("unroll")                                                     \
        for (int j_ = 0; j_ < 4; j_++)                                        \
            acc[i_][j_] = __builtin_amdgcn_mfma_f32_16x16x32_f16(             \
                AV[i_], BV[j_], acc[i_][j_], 0, 0, 0);                        \
    __builtin_amdgcn_s_setprio(0);

// ---------------------------------------------------------------------------
// 256x256 C = A.B^T, register-rotated engine, BK=64, 512 thr, 8 waves.
// R5: 16x16x32 conflict-free frag pattern + ONE barrier per K-tile.
//   kt loop: stage(kt+1 -> buf^1) ; RD(half1) ; lgkm(12)->MM(half0) ;
//            lgkm(0) [all reads of buf drained BEFORE barrier] ;
//            vm(0)+BAR ; RD(half0' from buf^1) ; MM(half1).
//   - intra-wave overlap: RD(half0') + next stage issue under MM(half1);
//     waves drift between barriers -> LDS and MFMA pipes co-run.
//   - race-free: buf reads drained pre-BAR; buf^1 read only post vm(0)+BAR;
//     restage of a region is >= 1 barrier after its last read.
//   - lgkm ledger: enter kt with 12 outstanding (prev tail RD), +12 -> 24,
//     lgkm(12) drains oldest set, lgkm(0) drains rest. vm: 8/kt, 0 at gate.
// nkt >= 1 (call sites: 16 or 4*(by+1)).
// ---------------------------------------------------------------------------
__device__ __forceinline__ void gemm256_rr(
    const _Float16* __restrict__ A, const _Float16* __restrict__ B,
    int lda, int ldb, int nkt,
    _Float16 (&SA)[2][16384], _Float16 (&SB)[2][16384],
    floatx4 (&acc)[8][4])
{
    const int t = threadIdx.x;
    const int wave = t >> 6, lane = t & 63;
    const int l15 = lane & 15, kq = lane >> 4;
    const int wm = wave >> 2, wn = wave & 3;

    const int aoff = (wm * 64 + l15) << 6;          // A frag row base (elts)
    const int boff = (wn * 16 + l15) << 6;          // B frag row base
    const int sl0 = ((kq ^ (l15 & 7)) << 3);        // k-half 0 swizzled slot
    const int sl1 = (((4 + kq) ^ (l15 & 7)) << 3);  // k-half 1

    const _Float16* A128 = A + (size_t)128 * lda;
    const _Float16* B128 = B + (size_t)128 * ldb;

    half8 a0[8], b0[4], a1[8], b1[4];

    // Prologue: stage K-tile 0 into buf0; preload half0 -> set0.
    stage128(A,    lda, 0, &SA[0][0],    wave, lane);
    stage128(A128, lda, 0, &SA[0][8192], wave, lane);
    stage128(B,    ldb, 0, &SB[0][0],    wave, lane);
    stage128(B128, ldb, 0, &SB[0][8192], wave, lane);
    WAIT_VM0; BAR; SCHED;
    RD_SET(a0, b0, 0, sl0);

    for (int kt = 0; kt < nkt; ++kt) {
        const int bs = kt & 1;
        const bool more = (kt + 1) < nkt;
        if (more) {
            const int k1 = (kt + 1) * 64;
            stage128(A,    lda, k1, &SA[bs ^ 1][0],    wave, lane);
            stage128(A128, lda, k1, &SA[bs ^ 1][8192], wave, lane);
            stage128(B,    ldb, k1, &SB[bs ^ 1][0],    wave, lane);
            stage128(B128, ldb, k1, &SB[bs ^ 1][8192], wave, lane);
        }
        RD_SET(a1, b1, bs, sl1);
        WAIT_LGKM12; SCHED;
        MM_SET(a0, b0);                 // k-half 0
        WAIT_LGKM0; SCHED;              // all reads of buf done pre-barrier
        if (more) {
            WAIT_VM0;                   // kt+1 tile landed in buf^1
            BAR; SCHED;
            RD_SET(a0, b0, bs ^ 1, sl0);// next tile half0; overlaps MM below
        }
        MM_SET(a1, b1);                 // k-half 1
    }
}

// ---------------------------------------------------------------------------
// Kernel 1: fp32 -> fp16, vectorized float4 -> half4.  (unchanged)
// ---------------------------------------------------------------------------
__global__ __launch_bounds__(256) void convert_inputs(
    const float* __restrict__ src,
    const float* __restrict__ Wk, const float* __restrict__ Wv, const float* __restrict__ Wq,
    _Float16* __restrict__ Xh, _Float16* __restrict__ Wh)
{
    const int gid = blockIdx.x * 256 + threadIdx.x;
    const int gs  = gridDim.x * 256;
    const int nX4 = BATCH * SEQ * DM / 4;
    const int nW4 = DM * DM / 4;
    const float4v* s4  = (const float4v*)src;
    const float4v* wk4 = (const float4v*)Wk;
    const float4v* wv4 = (const float4v*)Wv;
    const float4v* wq4 = (const float4v*)Wq;
    half4v* x4 = (half4v*)Xh;
    half4v* w4 = (half4v*)Wh;
    for (int i = gid; i < nX4; i += gs) {
        float4v v = s4[i];
        half4v h;
        #pragma unroll
        for (int e = 0; e < 4; e++) h[e] = (_Float16)v[e];
        x4[i] = h;
    }
    for (int i = gid; i < nW4; i += gs) {
        float4v a = wk4[i], b = wv4[i], c = wq4[i];
        half4v ha, hb, hc;
        #pragma unroll
        for (int e = 0; e < 4; e++) { ha[e] = (_Float16)a[e]; hb[e] = (_Float16)b[e]; hc[e] = (_Float16)c[e]; }
        w4[i]           = ha;
        w4[nW4 + i]     = hb;
        w4[2 * nW4 + i] = hc;
    }
}

// ---------------------------------------------------------------------------
// Kernel 2: QKV projection, 768 blocks x 512 thr, 256^2 tiles, XCD-bijective.
//   z=0: K[s][d]  = X.Wk^T + bk
//   z=1: Vt[d][s] = Wv.X^T + bv[d]
//   z=2: Q[s][d]  = X.Wq^T + bq
// C/D map (16x16x32): col = lane&15, row = (lane>>4)*4 + reg.
// ---------------------------------------------------------------------------
__global__ __launch_bounds__(512, 2) void qkv_gemm(
    const _Float16* __restrict__ Xh, const _Float16* __restrict__ Wh,
    const float* __restrict__ bk, const float* __restrict__ bv, const float* __restrict__ bq,
    _Float16* __restrict__ Kh, _Float16* __restrict__ Vt, _Float16* __restrict__ Qh)
{
    __shared__ __align__(16) _Float16 SA[2][16384];
    __shared__ __align__(16) _Float16 SB[2][16384];
    const int L = blockIdx.x;                 // 768 = 8 XCD x 96
    const int lid = (L & 7) * 96 + (L >> 3);
    const int z = lid >> 8;
    const int r = lid & 255;
    int by, bx;
    const _Float16 *A, *B;
    if (z == 1) {
        by = r & 3; bx = r >> 2;              // consecutive lids share X panel
        A = Wh + (size_t)DM * DM + (size_t)by * 256 * DM;
        B = Xh + (size_t)bx * 256 * DM;
    } else {
        by = r >> 2; bx = r & 3;              // consecutive lids share X panel
        A = Xh + (size_t)by * 256 * DM;
        B = Wh + (z ? (size_t)2 * DM * DM : (size_t)0) + (size_t)bx * 256 * DM;
    }
    floatx4 acc[8][4] = {};
    gemm256_rr(A, B, DM, DM, 16, SA, SB, acc);

    const int t = threadIdx.x, wave = t >> 6, lane = t & 63;
    const int l15 = lane & 15, kq = lane >> 4;
    const int wm = wave >> 2, wn = wave & 3;
    if (z == 1) {
        #pragma unroll
        for (int i = 0; i < 8; i++)
            #pragma unroll
            for (int j = 0; j < 4; j++)
                #pragma unroll
                for (int rr = 0; rr < 4; rr++) {
                    const int d  = by * 256 + wm * 64 + (i & 3) * 16 + (i >> 2) * 128 + kq * 4 + rr;
                    const int sg = bx * 256 + wn * 16 + (j & 1) * 64 + (j >> 1) * 128 + l15;
                    const int b = sg >> 11, s = sg & (SEQ - 1);
                    Vt[((size_t)b * DM + d) * SEQ + s] = (_Float16)(acc[i][j][rr] + bv[d]);
                }
    } else {
        const float* bias = z ? bq : bk;
        _Float16* outp    = z ? Qh : Kh;
        #pragma unroll
        for (int i = 0; i < 8; i++)
            #pragma unroll
            for (int j = 0; j < 4; j++)
                #pragma unroll
                for (int rr = 0; rr < 4; rr++) {
                    const int row = by * 256 + wm * 64 + (i & 3) * 16 + (i >> 2) * 128 + kq * 4 + rr;
                    const int col = bx * 256 + wn * 16 + (j & 1) * 64 + (j >> 1) * 128 + l15;
                    outp[(size_t)row * DM + col] = (_Float16)(acc[i][j][rr] + bias[col]);
                }
    }
}

// ---------------------------------------------------------------------------
// Kernel 3: scores (fp16) = Q.K^T * (1/32) + pad[b][k]; lower-tri 256-tiles.
// 288 blocks = 8 batches x 36 tri-tiles; XCD x owns batch x.
// ---------------------------------------------------------------------------
__global__ __launch_bounds__(512, 2) void scores_gemm(
    const _Float16* __restrict__ Qh, const _Float16* __restrict__ Kh,
    const float* __restrict__ pad, _Float16* __restrict__ Sc)
{
    __shared__ __align__(16) _Float16 SA[2][16384];
    __shared__ __align__(16) _Float16 SB[2][16384];
    const int L = blockIdx.x;                 // 288 = 8 XCD x 36
    const int lid = (L & 7) * 36 + (L >> 3);
    const int b = lid / 36, tri = lid - b * 36;
    int by = 0;
    #pragma unroll
    for (int u = 1; u <= 7; u++) if (tri >= (u * (u + 1)) / 2) by = u;
    const int bx = tri - (by * (by + 1)) / 2;

    const _Float16* A = Qh + ((size_t)b * SEQ + by * 256) * DM;
    const _Float16* B = Kh + ((size_t)b * SEQ + bx * 256) * DM;
    floatx4 acc[8][4] = {};
    gemm256_rr(A, B, DM, DM, 16, SA, SB, acc);

    const int t = threadIdx.x, wave = t >> 6, lane = t & 63;
    const int l15 = lane & 15, kq = lane >> 4;
    const int wm = wave >> 2, wn = wave & 3;
    #pragma unroll
    for (int i = 0; i < 8; i++)
        #pragma unroll
        for (int j = 0; j < 4; j++)
            #pragma unroll
            for (int rr = 0; rr < 4; rr++) {
                const int row = by * 256 + wm * 64 + (i & 3) * 16 + (i >> 2) * 128 + kq * 4 + rr;
                const int col = bx * 256 + wn * 16 + (j & 1) * 64 + (j >> 1) * 128 + l15;
                Sc[((size_t)b * SEQ + row) * SEQ + col] =
                    (_Float16)(acc[i][j][rr] * 0.03125f + pad[b * SEQ + col]);
            }
}

// ---------------------------------------------------------------------------
// Kernel 4: in-place row softmax over k in [0,q]; zeros for k in (q, kmaxr).
// kmaxr 256-granular (pv reads 256-wide tiles).
// ---------------------------------------------------------------------------
__global__ __launch_bounds__(256) void softmax_rows(_Float16* __restrict__ Sc)
{
    const int bid = blockIdx.x;
    const int b = bid >> 11, q = bid & (SEQ - 1);
    _Float16* row = Sc + ((size_t)b * SEQ + q) * SEQ;
    const int n = q + 1;
    const int kmaxr = ((q >> 8) + 1) << 8;
    const int t = threadIdx.x;
    const int c0 = t * 8;
    const bool active = (c0 < kmaxr);
    __shared__ float red[4];

    half8 v = {};
    if (active) v = *(const half8*)(row + c0);
    float f[8];
    float m = -3.0e38f;
    #pragma unroll
    for (int e = 0; e < 8; e++) {
        f[e] = (active && (c0 + e < n)) ? (float)v[e] : -3.0e38f;
        m = fmaxf(m, f[e]);
    }
    #pragma unroll
    for (int o = 32; o > 0; o >>= 1) m = fmaxf(m, __shfl_down(m, o));
    if ((t & 63) == 0) red[t >> 6] = m;
    __syncthreads();
    m = fmaxf(fmaxf(red[0], red[1]), fmaxf(red[2], red[3]));

    float ex[8], s = 0.f;
    #pragma unroll
    for (int e = 0; e < 8; e++) {
        ex[e] = (f[e] > -1.0e38f) ? __expf(f[e] - m) : 0.f;
        s += ex[e];
    }
    #pragma unroll
    for (int o = 32; o > 0; o >>= 1) s += __shfl_down(s, o);
    __syncthreads();
    if ((t & 63) == 0) red[t >> 6] = s;
    __syncthreads();
    s = red[0] + red[1] + red[2] + red[3];

    if (active) {
        const float inv = 1.0f / s;
        half8 o8;
        #pragma unroll
        for (int e = 0; e < 8; e++) o8[e] = (_Float16)(ex[e] * inv);
        *(half8*)(row + c0) = o8;
    }
}

// ---------------------------------------------------------------------------
// Kernel 5: O[q][d] = sum_k P[q][k] * Vt[d][k]; K-loop stops after q-tile.
// 256 blocks, 1/CU; XCD x owns batch x; longest tiles (by=7) first.
// ---------------------------------------------------------------------------
__global__ __launch_bounds__(512, 2) void pv_gemm(
    const _Float16* __restrict__ P, const _Float16* __restrict__ Vt,
    float* __restrict__ out)
{
    __shared__ __align__(16) _Float16 SA[2][16384];
    __shared__ __align__(16) _Float16 SB[2][16384];
    const int L = blockIdx.x;                 // 256 = 8 XCD x 32
    const int lid = (L & 7) * 32 + (L >> 3);
    const int b = lid >> 5, r = lid & 31;
    const int by = 7 - (r >> 2);              // long tiles first
    const int bx = r & 3;

    const _Float16* A = P  + ((size_t)b * SEQ + by * 256) * SEQ;
    const _Float16* B = Vt + ((size_t)b * DM  + bx * 256) * SEQ;
    const int nkt = (by + 1) * 4;             // K = (by+1)*256, P zero beyond
    floatx4 acc[8][4] = {};
    gemm256_rr(A, B, SEQ, SEQ, nkt, SA, SB, acc);

    const int t = threadIdx.x, wave = t >> 6, lane = t & 63;
    const int l15 = lane & 15, kq = lane >> 4;
    const int wm = wave >> 2, wn = wave & 3;
    #pragma unroll
    for (int i = 0; i < 8; i++)
        #pragma unroll
        for (int j = 0; j < 4; j++)
            #pragma unroll
            for (int rr = 0; rr < 4; rr++) {
                const int row = by * 256 + wm * 64 + (i & 3) * 16 + (i >> 2) * 128 + kq * 4 + rr;
                const int col = bx * 256 + wn * 16 + (j & 1) * 64 + (j >> 1) * 128 + l15;
                out[((size_t)b * SEQ + row) * DM + col] = acc[i][j][rr];
            }
}

// ---------------------------------------------------------------------------
// Workspace layout (bytes) — total 174,063,616:
//   Wh @ 0         :  6,291,456  (3x1024x1024 fp16)
//   Qh @ 6291456   : 33,554,432
//   Kh @ 39845888  : 33,554,432
//   Vt @ 73400320  : 33,554,432  ([B][D][S] fp16, written directly by qkv z=1)
//   Sc @ 106954752 : 67,108,864  (8x2048x2048 fp16; softmax in-place -> P)
// Xh (fp16 src, 33.5 MB) lives in d_out; dead before pv_gemm writes out.
// ---------------------------------------------------------------------------
extern "C" void kernel_launch(void* const* d_in, const int* in_sizes, int n_in,
                              void* d_out, int out_size, void* d_ws, size_t ws_size,
                              hipStream_t stream) {
    const float* src = (const float*)d_in[0];
    const float* pad = (const float*)d_in[1];
    // d_in[2] = causal mask, handled analytically
    const float* Wk = (const float*)d_in[3];
    const float* bk = (const float*)d_in[4];
    const float* Wv = (const float*)d_in[5];
    const float* bv = (const float*)d_in[6];
    const float* Wq = (const float*)d_in[7];
    const float* bq = (const float*)d_in[8];
    float* out = (float*)d_out;

    char* ws = (char*)d_ws;
    _Float16* Wh = (_Float16*)(ws);
    _Float16* Qh = (_Float16*)(ws + 6291456);
    _Float16* Kh = (_Float16*)(ws + 39845888);
    _Float16* Vt = (_Float16*)(ws + 73400320);
    _Float16* Sc = (_Float16*)(ws + 106954752);
    _Float16* Xh = (_Float16*)d_out;  // scratch inside out buffer

    convert_inputs<<<2048, 256, 0, stream>>>(src, Wk, Wv, Wq, Xh, Wh);
    qkv_gemm<<<768, 512, 0, stream>>>(Xh, Wh, bk, bv, bq, Kh, Vt, Qh);
    scores_gemm<<<288, 512, 0, stream>>>(Qh, Kh, pad, Sc);
    softmax_rows<<<BATCH * SEQ, 256, 0, stream>>>(Sc);
    pv_gemm<<<256, 512, 0, stream>>>(Sc, Vt, out);
}